// Round 1
// baseline (1391.349 us; speedup 1.0000x reference)
//
#include <hip/hip_runtime.h>
#include <hip/hip_bf16.h>

#define B_ 32
#define T_ 96
#define N_ 1024
#define ED_ 64
#define FFT_ 49
#define TOPK_ 30

// ---------------- ws layout (floats) ----------------
#define OFF_TWC   0u
#define OFF_TWS   4704u
#define OFF_XN1   9408u
#define OFF_RIN2  1615040u
#define OFF_XF    1616608u
#define OFF_X1    3713760u
#define OFF_PART  5810912u
#define OFF_STATS 5811424u
#define OFF_DEW   5811488u

// ---------------- wave helpers ----------------
__device__ __forceinline__ float wsum(float x){
  #pragma unroll
  for (int o = 32; o > 0; o >>= 1) x += __shfl_xor(x, o, 64);
  return x;
}
__device__ __forceinline__ int wsumi(int x){
  #pragma unroll
  for (int o = 32; o > 0; o >>= 1) x += __shfl_xor(x, o, 64);
  return x;
}
__device__ __forceinline__ float wmax(float x){
  #pragma unroll
  for (int o = 32; o > 0; o >>= 1) x = fmaxf(x, __shfl_xor(x, o, 64));
  return x;
}

// ---------------- K0: twiddle tables (transposed [t][f]) ----------------
__global__ void k_tw(float* __restrict__ twCt, float* __restrict__ twSt){
  int idx = blockIdx.x * 256 + threadIdx.x;
  if (idx < T_ * FFT_){
    int t = idx / FFT_, f = idx % FFT_;
    int k = (f * t) % T_;
    float ang = (float)k * 0.06544984694978736f; // 2*pi/96
    twCt[idx] = cosf(ang);
    twSt[idx] = sinf(ang);
  }
}

// ---------------- K1: DFT magnitude + axis-1 (freq) normalize ----------------
template<int F0, int NF>
__device__ __forceinline__ void dft_half(const float (*xs)[128], const float* __restrict__ twCt,
                                         const float* __restrict__ twSt, int n, float* mag, float* ssOut){
  float re[NF], im[NF];
  #pragma unroll
  for (int j = 0; j < NF; ++j){ re[j] = 0.f; im[j] = 0.f; }
  for (int t = 0; t < T_; ++t){
    float xv = xs[t][n];
    const float* c = twCt + t * FFT_ + F0;
    const float* s = twSt + t * FFT_ + F0;
    #pragma unroll
    for (int j = 0; j < NF; ++j){
      re[j] = fmaf(xv, c[j], re[j]);
      im[j] = fmaf(xv, s[j], im[j]);
    }
  }
  float ss = 0.f;
  #pragma unroll
  for (int j = 0; j < NF; ++j){
    float m = sqrtf(re[j]*re[j] + im[j]*im[j]);
    mag[j] = m; ss += m * m;
  }
  *ssOut = ss;
}

__global__ __launch_bounds__(256) void k_dft(const float* __restrict__ x, const float* __restrict__ twCt,
                                             const float* __restrict__ twSt, float* __restrict__ xn1){
  __shared__ float xs[T_][128];
  __shared__ float psum[2][128];
  int b = blockIdx.y, n0 = blockIdx.x * 128;
  int tid = threadIdx.x;
  for (int idx = tid; idx < T_ * 128; idx += 256){
    int t = idx >> 7, n = idx & 127;
    xs[t][n] = x[((size_t)b * T_ + t) * N_ + n0 + n];
  }
  __syncthreads();
  int n = tid & 127, half = tid >> 7;
  float mag[25]; float ss;
  if (half == 0) dft_half<0, 25>(xs, twCt, twSt, n, mag, &ss);
  else           dft_half<25, 24>(xs, twCt, twSt, n, mag, &ss);
  psum[half][n] = ss;
  __syncthreads();
  float rn = 1.f / fmaxf(sqrtf(psum[0][n] + psum[1][n]), 1e-12f);
  if (half == 0){
    #pragma unroll
    for (int j = 0; j < 25; ++j) xn1[((size_t)b * FFT_ + j) * N_ + n0 + n] = mag[j] * rn;
  } else {
    #pragma unroll
    for (int j = 0; j < 24; ++j) xn1[((size_t)b * FFT_ + 25 + j) * N_ + n0 + n] = mag[j] * rn;
  }
}

// ---------------- K1b: axis-2 (node) norm -> reciprocal ----------------
__global__ __launch_bounds__(256) void k_rin2(const float* __restrict__ xn1, float* __restrict__ rin2){
  int bf = blockIdx.x, tid = threadIdx.x;
  const float* p = xn1 + (size_t)bf * N_;
  float s = 0.f;
  #pragma unroll
  for (int it = 0; it < 4; ++it){ float v = p[tid + it * 256]; s += v * v; }
  s = wsum(s);
  __shared__ float sh[4];
  int lane = tid & 63, w = tid >> 6;
  if (lane == 0) sh[w] = s;
  __syncthreads();
  if (tid == 0){
    float tot = sh[0] + sh[1] + sh[2] + sh[3];
    rin2[bf] = 1.f / fmaxf(sqrtf(tot), 1e-12f);
  }
}

// ---------------- K2: xf[b,n,d] = sum_f xn2 * Wx ----------------
__global__ __launch_bounds__(256) void k_xf(const float* __restrict__ xn1, const float* __restrict__ rin2,
                                            const float* __restrict__ Wx, float* __restrict__ xf){
  __shared__ float Wp[FFT_][64];
  __shared__ float xnt[FFT_][64];
  int b = blockIdx.y, n0 = blockIdx.x * 64, tid = threadIdx.x;
  for (int idx = tid; idx < FFT_ * 64; idx += 256){
    int f = idx >> 6, d = idx & 63;
    Wp[f][d]  = Wx[idx] * rin2[b * FFT_ + f];
    xnt[f][d] = xn1[((size_t)b * FFT_ + f) * N_ + n0 + d];
  }
  __syncthreads();
  int n = tid & 63, dg = tid >> 6, d0 = dg * 16;
  float acc[16] = {};
  for (int f = 0; f < FFT_; ++f){
    float xv = xnt[f][n];
    #pragma unroll
    for (int j = 0; j < 16; ++j) acc[j] = fmaf(xv, Wp[f][d0 + j], acc[j]);
  }
  float* op = xf + ((size_t)b * N_ + n0 + n) * ED_ + d0;
  #pragma unroll
  for (int q = 0; q < 4; ++q)
    *(float4*)(op + q * 4) = make_float4(acc[q*4], acc[q*4+1], acc[q*4+2], acc[q*4+3]);
}

// ---------------- K3: x1 = relu(xedw @ Wd[n]) ----------------
__global__ __launch_bounds__(256) void k_x1(const float* __restrict__ xf, const float* __restrict__ E,
                                            const float* __restrict__ T_D, const float* __restrict__ D_W,
                                            const float* __restrict__ Wd, float* __restrict__ x1){
  __shared__ float xe[B_][257];
  __shared__ float Ws[64][68];
  int nn = blockIdx.x, tid = threadIdx.x;
  for (int idx = tid; idx < B_ * 256; idx += 256){
    int bb = idx >> 8, f = idx & 255;
    size_t bn = ((size_t)bb * N_ + nn) * ED_;
    float vv;
    if (f < 64)       vv = xf[bn + f];
    else if (f < 128) vv = E[nn * ED_ + (f - 64)];
    else if (f < 192) vv = T_D[bn + (f - 128)];
    else              vv = D_W[bn + (f - 192)];
    xe[bb][f] = vv;
  }
  int bb = tid >> 3, eg = tid & 7, e0 = eg * 8;
  float acc[8] = {};
  const float4* Wd4 = (const float4*)(Wd + (size_t)nn * 256 * ED_);
  for (int c = 0; c < 4; ++c){
    __syncthreads();
    for (int idx = tid; idx < 1024; idx += 256){
      float4 w = Wd4[c * 1024 + idx];
      int fl = idx >> 4, e = (idx & 15) * 4;
      *(float4*)(&Ws[fl][e]) = w;
    }
    __syncthreads();
    for (int fl = 0; fl < 64; ++fl){
      float xv = xe[bb][c * 64 + fl];
      float4 w0 = *(const float4*)(&Ws[fl][e0]);
      float4 w1 = *(const float4*)(&Ws[fl][e0 + 4]);
      acc[0] = fmaf(xv, w0.x, acc[0]); acc[1] = fmaf(xv, w0.y, acc[1]);
      acc[2] = fmaf(xv, w0.z, acc[2]); acc[3] = fmaf(xv, w0.w, acc[3]);
      acc[4] = fmaf(xv, w1.x, acc[4]); acc[5] = fmaf(xv, w1.y, acc[5]);
      acc[6] = fmaf(xv, w1.z, acc[6]); acc[7] = fmaf(xv, w1.w, acc[7]);
    }
  }
  float* op = x1 + ((size_t)bb * N_ + nn) * ED_ + e0;
  float4 o0 = make_float4(fmaxf(acc[0],0.f), fmaxf(acc[1],0.f), fmaxf(acc[2],0.f), fmaxf(acc[3],0.f));
  float4 o1 = make_float4(fmaxf(acc[4],0.f), fmaxf(acc[5],0.f), fmaxf(acc[6],0.f), fmaxf(acc[7],0.f));
  *(float4*)(op) = o0;
  *(float4*)(op + 4) = o1;
}

// ---------------- K4a/K4b: LayerNorm stats over [N,ED] per batch ----------------
__global__ __launch_bounds__(256) void k_stats1(const float* __restrict__ x1, float2* __restrict__ part){
  int blk = blockIdx.x, b = blk >> 3, seg = blk & 7;
  const float4* p = (const float4*)(x1 + (size_t)b * 65536 + seg * 8192);
  int tid = threadIdx.x;
  float s1 = 0.f, s2 = 0.f;
  #pragma unroll
  for (int it = 0; it < 8; ++it){
    float4 v = p[tid + it * 256];
    s1 += v.x + v.y + v.z + v.w;
    s2 += v.x*v.x + v.y*v.y + v.z*v.z + v.w*v.w;
  }
  s1 = wsum(s1); s2 = wsum(s2);
  __shared__ float sh[2][4];
  int lane = tid & 63, w = tid >> 6;
  if (lane == 0){ sh[0][w] = s1; sh[1][w] = s2; }
  __syncthreads();
  if (tid == 0)
    part[blk] = make_float2(sh[0][0]+sh[0][1]+sh[0][2]+sh[0][3],
                            sh[1][0]+sh[1][1]+sh[1][2]+sh[1][3]);
}

__global__ void k_stats2(const float2* __restrict__ part, float* __restrict__ stats){
  int b = threadIdx.x;
  if (b < B_){
    float s1 = 0.f, s2 = 0.f;
    for (int j = 0; j < 8; ++j){ float2 v = part[b * 8 + j]; s1 += v.x; s2 += v.y; }
    float mu = s1 * (1.f / 65536.f);
    float var = s2 * (1.f / 65536.f) - mu * mu;
    stats[b * 2]     = mu;
    stats[b * 2 + 1] = rsqrtf(var + 1e-8f);
  }
}

// ---------------- K5: DEw = ((x1-mu)*rstd) @ Wxabs ----------------
__global__ __launch_bounds__(256) void k_dew(const float* __restrict__ x1, const float* __restrict__ Wxabs,
                                             const float* __restrict__ stats, float* __restrict__ DEw){
  __shared__ float Ws[64][68];
  __shared__ float x1s[16][68];
  __shared__ float cs[64];
  int b = blockIdx.y, n0 = blockIdx.x * 16, tid = threadIdx.x;
  for (int idx = tid; idx < 1024; idx += 256){
    float4 w = ((const float4*)Wxabs)[idx];
    int e = idx >> 4, k = (idx & 15) * 4;
    *(float4*)(&Ws[e][k]) = w;
  }
  {
    int idx = tid; // 256 float4 = whole tile
    float4 v = ((const float4*)(x1 + ((size_t)b * N_ + n0) * ED_))[idx];
    int n = idx >> 4, e = (idx & 15) * 4;
    *(float4*)(&x1s[n][e]) = v;
  }
  __syncthreads();
  if (tid < 64){
    float s = 0.f;
    for (int e = 0; e < 64; ++e) s += Ws[e][tid];
    cs[tid] = s;
  }
  __syncthreads();
  int n = tid & 15, kg = tid >> 4, k0 = kg * 4;
  float mu = stats[b * 2], rstd = stats[b * 2 + 1];
  float acc[4] = {};
  for (int e = 0; e < 64; ++e){
    float xv = x1s[n][e];
    #pragma unroll
    for (int j = 0; j < 4; ++j) acc[j] = fmaf(xv, Ws[e][k0 + j], acc[j]);
  }
  float4 o;
  o.x = rstd * (acc[0] - mu * cs[k0]);
  o.y = rstd * (acc[1] - mu * cs[k0 + 1]);
  o.z = rstd * (acc[2] - mu * cs[k0 + 2]);
  o.w = rstd * (acc[3] - mu * cs[k0 + 3]);
  *(float4*)(DEw + ((size_t)b * N_ + n0 + n) * ED_ + k0) = o;
}

// ---------------- K6: adj = relu(DEw @ x1^T) -> d_out ----------------
__global__ __launch_bounds__(256) void k_adj(const float* __restrict__ DEw, const float* __restrict__ x1,
                                             float* __restrict__ out){
  __shared__ float At[64][132];
  __shared__ float Bt[64][132];
  int b = blockIdx.z;
  int nb = blockIdx.y * 128, mb = blockIdx.x * 128;
  int tid = threadIdx.x;
  const float4* A4 = (const float4*)(DEw + ((size_t)b * N_ + nb) * ED_);
  const float4* Bq = (const float4*)(x1  + ((size_t)b * N_ + mb) * ED_);
  for (int idx = tid; idx < 2048; idx += 256){
    int r = idx >> 4, k4 = idx & 15, k0 = k4 * 4;
    float4 a = A4[r * 16 + k4];
    At[k0][r] = a.x; At[k0+1][r] = a.y; At[k0+2][r] = a.z; At[k0+3][r] = a.w;
    float4 v = Bq[r * 16 + k4];
    Bt[k0][r] = v.x; Bt[k0+1][r] = v.y; Bt[k0+2][r] = v.z; Bt[k0+3][r] = v.w;
  }
  __syncthreads();
  int tn = tid >> 4, tm = tid & 15;
  float acc[8][8] = {};
  #pragma unroll 4
  for (int k = 0; k < 64; ++k){
    const float4* Ar = (const float4*)(&At[k][0]);
    const float4* Br = (const float4*)(&Bt[k][0]);
    float4 a0 = Ar[tn * 2], a1 = Ar[tn * 2 + 1];
    float4 b0 = Br[tm * 2], b1 = Br[tm * 2 + 1];
    float av[8] = {a0.x,a0.y,a0.z,a0.w,a1.x,a1.y,a1.z,a1.w};
    float bw[8] = {b0.x,b0.y,b0.z,b0.w,b1.x,b1.y,b1.z,b1.w};
    #pragma unroll
    for (int i = 0; i < 8; ++i)
      #pragma unroll
      for (int j = 0; j < 8; ++j)
        acc[i][j] = fmaf(av[i], bw[j], acc[i][j]);
  }
  size_t obase = ((size_t)b * N_ + nb + tn * 8) * N_ + mb + tm * 8;
  #pragma unroll
  for (int i = 0; i < 8; ++i){
    float4 o0 = make_float4(fmaxf(acc[i][0],0.f), fmaxf(acc[i][1],0.f), fmaxf(acc[i][2],0.f), fmaxf(acc[i][3],0.f));
    float4 o1 = make_float4(fmaxf(acc[i][4],0.f), fmaxf(acc[i][5],0.f), fmaxf(acc[i][6],0.f), fmaxf(acc[i][7],0.f));
    *(float4*)(out + obase + (size_t)i * N_)     = o0;
    *(float4*)(out + obase + (size_t)i * N_ + 4) = o1;
  }
}

// ---------------- K7: per-row exact top-30 mask + softmax (in place) ----------------
__global__ __launch_bounds__(256) void k_topk(float* __restrict__ out){
  int row = blockIdx.x * 4 + (threadIdx.x >> 6);
  int lane = threadIdx.x & 63;
  float* rp = out + (size_t)row * N_;
  float v[16];
  #pragma unroll
  for (int q = 0; q < 4; ++q){
    float4 t = *(const float4*)(rp + lane * 16 + q * 4);
    v[q*4] = t.x; v[q*4+1] = t.y; v[q*4+2] = t.z; v[q*4+3] = t.w;
  }
  float vmax = v[0];
  #pragma unroll
  for (int j = 1; j < 16; ++j) vmax = fmaxf(vmax, v[j]);
  vmax = wmax(vmax);

  // exact 30th-largest via binary search on (non-negative) float bit patterns
  unsigned lo = 0u, hi = __float_as_uint(vmax) + 1u;
  while (hi - lo > 1u){
    unsigned mid = lo + ((hi - lo) >> 1);
    float t = __uint_as_float(mid);
    int c = 0;
    #pragma unroll
    for (int j = 0; j < 16; ++j) c += (v[j] >= t) ? 1 : 0;
    c = wsumi(c);
    if (c >= TOPK_) lo = mid; else hi = mid;
  }
  float thr = __uint_as_float(lo);

  int cgt = 0, eqc = 0;
  #pragma unroll
  for (int j = 0; j < 16; ++j){ cgt += (v[j] > thr) ? 1 : 0; eqc += (v[j] == thr) ? 1 : 0; }
  cgt = wsumi(cgt);
  int keq = TOPK_ - cgt;

  // exclusive scan of per-lane equal counts (index order = lane-major, j-minor)
  int sc = eqc;
  #pragma unroll
  for (int off = 1; off < 64; off <<= 1){
    int t = __shfl_up(sc, off, 64);
    if (lane >= off) sc += t;
  }
  int run = sc - eqc;

  float z = 0.f; float p[16];
  #pragma unroll
  for (int j = 0; j < 16; ++j){
    bool eq = (v[j] == thr);
    bool sel = (v[j] > thr) || (eq && (run < keq));
    run += eq ? 1 : 0;
    float e = __expf((sel ? v[j] : 0.f) - vmax);
    p[j] = e; z += e;
  }
  z = wsum(z);
  float rz = 1.f / z;
  #pragma unroll
  for (int q = 0; q < 4; ++q){
    float4 t = make_float4(p[q*4]*rz, p[q*4+1]*rz, p[q*4+2]*rz, p[q*4+3]*rz);
    *(float4*)(rp + lane * 16 + q * 4) = t;
  }
}

// ---------------- launcher ----------------
extern "C" void kernel_launch(void* const* d_in, const int* in_sizes, int n_in,
                              void* d_out, int out_size, void* d_ws, size_t ws_size,
                              hipStream_t stream){
  const float* x     = (const float*)d_in[0];
  const float* T_D   = (const float*)d_in[1];
  const float* D_W   = (const float*)d_in[2];
  const float* E     = (const float*)d_in[3];
  const float* Wx    = (const float*)d_in[4];
  const float* Wd    = (const float*)d_in[5];
  const float* Wxabs = (const float*)d_in[6];
  float* out = (float*)d_out;
  float* ws  = (float*)d_ws;

  float* twCt  = ws + OFF_TWC;
  float* twSt  = ws + OFF_TWS;
  float* xn1   = ws + OFF_XN1;
  float* rin2  = ws + OFF_RIN2;
  float* xf    = ws + OFF_XF;
  float* x1    = ws + OFF_X1;
  float2* part = (float2*)(ws + OFF_PART);
  float* stats = ws + OFF_STATS;
  float* DEw   = ws + OFF_DEW;

  k_tw<<<19, 256, 0, stream>>>(twCt, twSt);
  k_dft<<<dim3(8, B_), 256, 0, stream>>>(x, twCt, twSt, xn1);
  k_rin2<<<B_ * FFT_, 256, 0, stream>>>(xn1, rin2);
  k_xf<<<dim3(16, B_), 256, 0, stream>>>(xn1, rin2, Wx, xf);
  k_x1<<<N_, 256, 0, stream>>>(xf, E, T_D, D_W, Wd, x1);
  k_stats1<<<256, 256, 0, stream>>>(x1, part);
  k_stats2<<<1, 64, 0, stream>>>(part, stats);
  k_dew<<<dim3(64, B_), 256, 0, stream>>>(x1, Wxabs, stats, DEw);
  k_adj<<<dim3(8, 8, B_), 256, 0, stream>>>(DEw, x1, out);
  k_topk<<<(B_ * N_) / 4, 256, 0, stream>>>(out);
}

// Round 3
// 423.256 us; speedup vs baseline: 3.2873x; 3.2873x over previous
//
#include <hip/hip_runtime.h>
#include <hip/hip_bf16.h>

#define B_ 32
#define T_ 96
#define N_ 1024
#define ED_ 64
#define FFT_ 49
#define TOPK_ 30

// ---------------- ws layout (floats) ----------------
#define OFF_TWC   0u
#define OFF_TWS   4704u
#define OFF_XN1   9408u
#define OFF_RIN2  1615040u
#define OFF_XF    1616608u
#define OFF_X1    3713760u
#define OFF_PART  5810912u
#define OFF_STATS 5811424u
#define OFF_DEW   5811488u

// ---------------- wave helpers ----------------
__device__ __forceinline__ float wsum(float x){
  #pragma unroll
  for (int o = 32; o > 0; o >>= 1) x += __shfl_xor(x, o, 64);
  return x;
}
__device__ __forceinline__ int wsumi(int x){
  #pragma unroll
  for (int o = 32; o > 0; o >>= 1) x += __shfl_xor(x, o, 64);
  return x;
}
__device__ __forceinline__ float wmax(float x){
  #pragma unroll
  for (int o = 32; o > 0; o >>= 1) x = fmaxf(x, __shfl_xor(x, o, 64));
  return x;
}

// ---------------- K0: twiddle tables (transposed [t][f]) ----------------
__global__ void k_tw(float* __restrict__ twCt, float* __restrict__ twSt){
  int idx = blockIdx.x * 256 + threadIdx.x;
  if (idx < T_ * FFT_){
    int t = idx / FFT_, f = idx % FFT_;
    int k = (f * t) % T_;
    float ang = (float)k * 0.06544984694978736f; // 2*pi/96
    twCt[idx] = cosf(ang);
    twSt[idx] = sinf(ang);
  }
}

// ---------------- K1: DFT magnitude + axis-1 (freq) normalize ----------------
template<int F0, int NF>
__device__ __forceinline__ void dft_half(const float (*xs)[128], const float* __restrict__ twCt,
                                         const float* __restrict__ twSt, int n, float* mag, float* ssOut){
  float re[NF], im[NF];
  #pragma unroll
  for (int j = 0; j < NF; ++j){ re[j] = 0.f; im[j] = 0.f; }
  for (int t = 0; t < T_; ++t){
    float xv = xs[t][n];
    const float* c = twCt + t * FFT_ + F0;
    const float* s = twSt + t * FFT_ + F0;
    #pragma unroll
    for (int j = 0; j < NF; ++j){
      re[j] = fmaf(xv, c[j], re[j]);
      im[j] = fmaf(xv, s[j], im[j]);
    }
  }
  float ss = 0.f;
  #pragma unroll
  for (int j = 0; j < NF; ++j){
    float m = sqrtf(re[j]*re[j] + im[j]*im[j]);
    mag[j] = m; ss += m * m;
  }
  *ssOut = ss;
}

__global__ __launch_bounds__(256) void k_dft(const float* __restrict__ x, const float* __restrict__ twCt,
                                             const float* __restrict__ twSt, float* __restrict__ xn1){
  __shared__ float xs[T_][128];
  __shared__ float psum[2][128];
  int b = blockIdx.y, n0 = blockIdx.x * 128;
  int tid = threadIdx.x;
  for (int idx = tid; idx < T_ * 128; idx += 256){
    int t = idx >> 7, n = idx & 127;
    xs[t][n] = x[((size_t)b * T_ + t) * N_ + n0 + n];
  }
  __syncthreads();
  int n = tid & 127, half = tid >> 7;
  float mag[25]; float ss;
  if (half == 0) dft_half<0, 25>(xs, twCt, twSt, n, mag, &ss);
  else           dft_half<25, 24>(xs, twCt, twSt, n, mag, &ss);
  psum[half][n] = ss;
  __syncthreads();
  float rn = 1.f / fmaxf(sqrtf(psum[0][n] + psum[1][n]), 1e-12f);
  if (half == 0){
    #pragma unroll
    for (int j = 0; j < 25; ++j) xn1[((size_t)b * FFT_ + j) * N_ + n0 + n] = mag[j] * rn;
  } else {
    #pragma unroll
    for (int j = 0; j < 24; ++j) xn1[((size_t)b * FFT_ + 25 + j) * N_ + n0 + n] = mag[j] * rn;
  }
}

// ---------------- K1b: axis-2 (node) norm -> reciprocal ----------------
__global__ __launch_bounds__(256) void k_rin2(const float* __restrict__ xn1, float* __restrict__ rin2){
  int bf = blockIdx.x, tid = threadIdx.x;
  const float* p = xn1 + (size_t)bf * N_;
  float s = 0.f;
  #pragma unroll
  for (int it = 0; it < 4; ++it){ float v = p[tid + it * 256]; s += v * v; }
  s = wsum(s);
  __shared__ float sh[4];
  int lane = tid & 63, w = tid >> 6;
  if (lane == 0) sh[w] = s;
  __syncthreads();
  if (tid == 0){
    float tot = sh[0] + sh[1] + sh[2] + sh[3];
    rin2[bf] = 1.f / fmaxf(sqrtf(tot), 1e-12f);
  }
}

// ---------------- K2: xf[b,n,d] = sum_f xn2 * Wx ----------------
__global__ __launch_bounds__(256) void k_xf(const float* __restrict__ xn1, const float* __restrict__ rin2,
                                            const float* __restrict__ Wx, float* __restrict__ xf){
  __shared__ float Wp[FFT_][64];
  __shared__ float xnt[FFT_][64];
  int b = blockIdx.y, n0 = blockIdx.x * 64, tid = threadIdx.x;
  for (int idx = tid; idx < FFT_ * 64; idx += 256){
    int f = idx >> 6, d = idx & 63;
    Wp[f][d]  = Wx[idx] * rin2[b * FFT_ + f];
    xnt[f][d] = xn1[((size_t)b * FFT_ + f) * N_ + n0 + d];
  }
  __syncthreads();
  int n = tid & 63, dg = tid >> 6, d0 = dg * 16;
  float acc[16] = {};
  for (int f = 0; f < FFT_; ++f){
    float xv = xnt[f][n];
    #pragma unroll
    for (int j = 0; j < 16; ++j) acc[j] = fmaf(xv, Wp[f][d0 + j], acc[j]);
  }
  float* op = xf + ((size_t)b * N_ + n0 + n) * ED_ + d0;
  #pragma unroll
  for (int q = 0; q < 4; ++q)
    *(float4*)(op + q * 4) = make_float4(acc[q*4], acc[q*4+1], acc[q*4+2], acc[q*4+3]);
}

// ---------------- K3: x1 = relu(xedw @ Wd[n]) ----------------
// Rewritten: __launch_bounds__(256,4) caps VGPR at 128 (old version ballooned
// to 256 VGPRs -> 1-2 blocks/CU -> 1 ms). Staging split into wave-uniform
// coalesced loops; inner loop unroll bounded.
__global__ __launch_bounds__(256, 4) void k_x1(const float* __restrict__ xf, const float* __restrict__ E,
                                               const float* __restrict__ T_D, const float* __restrict__ D_W,
                                               const float* __restrict__ Wd, float* __restrict__ x1){
  __shared__ float xe[B_][260];
  __shared__ float Ws[64][68];
  int nn = blockIdx.x, tid = threadIdx.x;

  // stage xedw[32][256]: separate coalesced loops, 4 batch-rows per iteration
  {
    int bb0 = tid >> 6, f = tid & 63;
    #pragma unroll 2
    for (int it = 0; it < 8; ++it){
      int b2 = bb0 + it * 4;
      size_t bn = ((size_t)b2 * N_ + nn) * ED_;
      xe[b2][f]       = xf[bn + f];
      xe[b2][128 + f] = T_D[bn + f];
      xe[b2][192 + f] = D_W[bn + f];
    }
    float ev = E[nn * ED_ + f];
    #pragma unroll
    for (int it = 0; it < 8; ++it) xe[bb0 + it * 4][64 + f] = ev;
  }

  int bb = tid >> 3, eg = tid & 7, e0 = eg * 8;
  float acc[8] = {};
  const float4* Wd4 = (const float4*)(Wd + (size_t)nn * 256 * ED_);
  for (int c = 0; c < 4; ++c){
    __syncthreads();
    #pragma unroll
    for (int it = 0; it < 4; ++it){
      int idx = tid + it * 256;
      float4 w = Wd4[c * 1024 + idx];
      int fl = idx >> 4, e = (idx & 15) * 4;
      *(float4*)(&Ws[fl][e]) = w;
    }
    __syncthreads();
    #pragma unroll 8
    for (int fl = 0; fl < 64; ++fl){
      float xv = xe[bb][c * 64 + fl];
      float4 w0 = *(const float4*)(&Ws[fl][e0]);
      float4 w1 = *(const float4*)(&Ws[fl][e0 + 4]);
      acc[0] = fmaf(xv, w0.x, acc[0]); acc[1] = fmaf(xv, w0.y, acc[1]);
      acc[2] = fmaf(xv, w0.z, acc[2]); acc[3] = fmaf(xv, w0.w, acc[3]);
      acc[4] = fmaf(xv, w1.x, acc[4]); acc[5] = fmaf(xv, w1.y, acc[5]);
      acc[6] = fmaf(xv, w1.z, acc[6]); acc[7] = fmaf(xv, w1.w, acc[7]);
    }
  }
  float* op = x1 + ((size_t)bb * N_ + nn) * ED_ + e0;
  float4 o0 = make_float4(fmaxf(acc[0],0.f), fmaxf(acc[1],0.f), fmaxf(acc[2],0.f), fmaxf(acc[3],0.f));
  float4 o1 = make_float4(fmaxf(acc[4],0.f), fmaxf(acc[5],0.f), fmaxf(acc[6],0.f), fmaxf(acc[7],0.f));
  *(float4*)(op) = o0;
  *(float4*)(op + 4) = o1;
}

// ---------------- K4a/K4b: LayerNorm stats over [N,ED] per batch ----------------
__global__ __launch_bounds__(256) void k_stats1(const float* __restrict__ x1, float2* __restrict__ part){
  int blk = blockIdx.x, b = blk >> 3, seg = blk & 7;
  const float4* p = (const float4*)(x1 + (size_t)b * 65536 + seg * 8192);
  int tid = threadIdx.x;
  float s1 = 0.f, s2 = 0.f;
  #pragma unroll
  for (int it = 0; it < 8; ++it){
    float4 v = p[tid + it * 256];
    s1 += v.x + v.y + v.z + v.w;
    s2 += v.x*v.x + v.y*v.y + v.z*v.z + v.w*v.w;
  }
  s1 = wsum(s1); s2 = wsum(s2);
  __shared__ float sh[2][4];
  int lane = tid & 63, w = tid >> 6;
  if (lane == 0){ sh[0][w] = s1; sh[1][w] = s2; }
  __syncthreads();
  if (tid == 0)
    part[blk] = make_float2(sh[0][0]+sh[0][1]+sh[0][2]+sh[0][3],
                            sh[1][0]+sh[1][1]+sh[1][2]+sh[1][3]);
}

__global__ void k_stats2(const float2* __restrict__ part, float* __restrict__ stats){
  int b = threadIdx.x;
  if (b < B_){
    float s1 = 0.f, s2 = 0.f;
    for (int j = 0; j < 8; ++j){ float2 v = part[b * 8 + j]; s1 += v.x; s2 += v.y; }
    float mu = s1 * (1.f / 65536.f);
    float var = s2 * (1.f / 65536.f) - mu * mu;
    stats[b * 2]     = mu;
    stats[b * 2 + 1] = rsqrtf(var + 1e-8f);
  }
}

// ---------------- K5: DEw = ((x1-mu)*rstd) @ Wxabs ----------------
__global__ __launch_bounds__(256) void k_dew(const float* __restrict__ x1, const float* __restrict__ Wxabs,
                                             const float* __restrict__ stats, float* __restrict__ DEw){
  __shared__ float Ws[64][68];
  __shared__ float x1s[16][68];
  __shared__ float cs[64];
  int b = blockIdx.y, n0 = blockIdx.x * 16, tid = threadIdx.x;
  for (int idx = tid; idx < 1024; idx += 256){
    float4 w = ((const float4*)Wxabs)[idx];
    int e = idx >> 4, k = (idx & 15) * 4;
    *(float4*)(&Ws[e][k]) = w;
  }
  {
    int idx = tid; // 256 float4 = whole tile
    float4 v = ((const float4*)(x1 + ((size_t)b * N_ + n0) * ED_))[idx];
    int n = idx >> 4, e = (idx & 15) * 4;
    *(float4*)(&x1s[n][e]) = v;
  }
  __syncthreads();
  if (tid < 64){
    float s = 0.f;
    for (int e = 0; e < 64; ++e) s += Ws[e][tid];
    cs[tid] = s;
  }
  __syncthreads();
  int n = tid & 15, kg = tid >> 4, k0 = kg * 4;
  float mu = stats[b * 2], rstd = stats[b * 2 + 1];
  float acc[4] = {};
  for (int e = 0; e < 64; ++e){
    float xv = x1s[n][e];
    #pragma unroll
    for (int j = 0; j < 4; ++j) acc[j] = fmaf(xv, Ws[e][k0 + j], acc[j]);
  }
  float4 o;
  o.x = rstd * (acc[0] - mu * cs[k0]);
  o.y = rstd * (acc[1] - mu * cs[k0 + 1]);
  o.z = rstd * (acc[2] - mu * cs[k0 + 2]);
  o.w = rstd * (acc[3] - mu * cs[k0 + 3]);
  *(float4*)(DEw + ((size_t)b * N_ + n0 + n) * ED_ + k0) = o;
}

// ---------------- K6: adj = relu(DEw @ x1^T) -> d_out ----------------
__global__ __launch_bounds__(256) void k_adj(const float* __restrict__ DEw, const float* __restrict__ x1,
                                             float* __restrict__ out){
  __shared__ float At[64][132];
  __shared__ float Bt[64][132];
  int b = blockIdx.z;
  int nb = blockIdx.y * 128, mb = blockIdx.x * 128;
  int tid = threadIdx.x;
  const float4* A4 = (const float4*)(DEw + ((size_t)b * N_ + nb) * ED_);
  const float4* Bq = (const float4*)(x1  + ((size_t)b * N_ + mb) * ED_);
  for (int idx = tid; idx < 2048; idx += 256){
    int r = idx >> 4, k4 = idx & 15, k0 = k4 * 4;
    float4 a = A4[r * 16 + k4];
    At[k0][r] = a.x; At[k0+1][r] = a.y; At[k0+2][r] = a.z; At[k0+3][r] = a.w;
    float4 v = Bq[r * 16 + k4];
    Bt[k0][r] = v.x; Bt[k0+1][r] = v.y; Bt[k0+2][r] = v.z; Bt[k0+3][r] = v.w;
  }
  __syncthreads();
  int tn = tid >> 4, tm = tid & 15;
  float acc[8][8] = {};
  #pragma unroll 4
  for (int k = 0; k < 64; ++k){
    const float4* Ar = (const float4*)(&At[k][0]);
    const float4* Br = (const float4*)(&Bt[k][0]);
    float4 a0 = Ar[tn * 2], a1 = Ar[tn * 2 + 1];
    float4 b0 = Br[tm * 2], b1 = Br[tm * 2 + 1];
    float av[8] = {a0.x,a0.y,a0.z,a0.w,a1.x,a1.y,a1.z,a1.w};
    float bw[8] = {b0.x,b0.y,b0.z,b0.w,b1.x,b1.y,b1.z,b1.w};
    #pragma unroll
    for (int i = 0; i < 8; ++i)
      #pragma unroll
      for (int j = 0; j < 8; ++j)
        acc[i][j] = fmaf(av[i], bw[j], acc[i][j]);
  }
  size_t obase = ((size_t)b * N_ + nb + tn * 8) * N_ + mb + tm * 8;
  #pragma unroll
  for (int i = 0; i < 8; ++i){
    float4 o0 = make_float4(fmaxf(acc[i][0],0.f), fmaxf(acc[i][1],0.f), fmaxf(acc[i][2],0.f), fmaxf(acc[i][3],0.f));
    float4 o1 = make_float4(fmaxf(acc[i][4],0.f), fmaxf(acc[i][5],0.f), fmaxf(acc[i][6],0.f), fmaxf(acc[i][7],0.f));
    *(float4*)(out + obase + (size_t)i * N_)     = o0;
    *(float4*)(out + obase + (size_t)i * N_ + 4) = o1;
  }
}

// ---------------- K7: per-row exact top-30 mask + softmax (in place) ----------------
__global__ __launch_bounds__(256) void k_topk(float* __restrict__ out){
  int row = blockIdx.x * 4 + (threadIdx.x >> 6);
  int lane = threadIdx.x & 63;
  float* rp = out + (size_t)row * N_;
  float v[16];
  #pragma unroll
  for (int q = 0; q < 4; ++q){
    float4 t = *(const float4*)(rp + lane * 16 + q * 4);
    v[q*4] = t.x; v[q*4+1] = t.y; v[q*4+2] = t.z; v[q*4+3] = t.w;
  }
  float vmax = v[0];
  #pragma unroll
  for (int j = 1; j < 16; ++j) vmax = fmaxf(vmax, v[j]);
  vmax = wmax(vmax);

  // exact 30th-largest via binary search on (non-negative) float bit patterns
  unsigned lo = 0u, hi = __float_as_uint(vmax) + 1u;
  while (hi - lo > 1u){
    unsigned mid = lo + ((hi - lo) >> 1);
    float t = __uint_as_float(mid);
    int c = 0;
    #pragma unroll
    for (int j = 0; j < 16; ++j) c += (v[j] >= t) ? 1 : 0;
    c = wsumi(c);
    if (c >= TOPK_) lo = mid; else hi = mid;
  }
  float thr = __uint_as_float(lo);

  int cgt = 0, eqc = 0;
  #pragma unroll
  for (int j = 0; j < 16; ++j){ cgt += (v[j] > thr) ? 1 : 0; eqc += (v[j] == thr) ? 1 : 0; }
  cgt = wsumi(cgt);
  int keq = TOPK_ - cgt;

  // exclusive scan of per-lane equal counts (index order = lane-major, j-minor)
  int sc = eqc;
  #pragma unroll
  for (int off = 1; off < 64; off <<= 1){
    int t = __shfl_up(sc, off, 64);
    if (lane >= off) sc += t;
  }
  int run = sc - eqc;

  float z = 0.f; float p[16];
  #pragma unroll
  for (int j = 0; j < 16; ++j){
    bool eq = (v[j] == thr);
    bool sel = (v[j] > thr) || (eq && (run < keq));
    run += eq ? 1 : 0;
    float e = __expf((sel ? v[j] : 0.f) - vmax);
    p[j] = e; z += e;
  }
  z = wsum(z);
  float rz = 1.f / z;
  #pragma unroll
  for (int q = 0; q < 4; ++q){
    float4 t = make_float4(p[q*4]*rz, p[q*4+1]*rz, p[q*4+2]*rz, p[q*4+3]*rz);
    *(float4*)(rp + lane * 16 + q * 4) = t;
  }
}

// ---------------- launcher ----------------
extern "C" void kernel_launch(void* const* d_in, const int* in_sizes, int n_in,
                              void* d_out, int out_size, void* d_ws, size_t ws_size,
                              hipStream_t stream){
  const float* x     = (const float*)d_in[0];
  const float* T_D   = (const float*)d_in[1];
  const float* D_W   = (const float*)d_in[2];
  const float* E     = (const float*)d_in[3];
  const float* Wx    = (const float*)d_in[4];
  const float* Wd    = (const float*)d_in[5];
  const float* Wxabs = (const float*)d_in[6];
  float* out = (float*)d_out;
  float* ws  = (float*)d_ws;

  float* twCt  = ws + OFF_TWC;
  float* twSt  = ws + OFF_TWS;
  float* xn1   = ws + OFF_XN1;
  float* rin2  = ws + OFF_RIN2;
  float* xf    = ws + OFF_XF;
  float* x1    = ws + OFF_X1;
  float2* part = (float2*)(ws + OFF_PART);
  float* stats = ws + OFF_STATS;
  float* DEw   = ws + OFF_DEW;

  k_tw<<<19, 256, 0, stream>>>(twCt, twSt);
  k_dft<<<dim3(8, B_), 256, 0, stream>>>(x, twCt, twSt, xn1);
  k_rin2<<<B_ * FFT_, 256, 0, stream>>>(xn1, rin2);
  k_xf<<<dim3(16, B_), 256, 0, stream>>>(xn1, rin2, Wx, xf);
  k_x1<<<N_, 256, 0, stream>>>(xf, E, T_D, D_W, Wd, x1);
  k_stats1<<<256, 256, 0, stream>>>(x1, part);
  k_stats2<<<1, 64, 0, stream>>>(part, stats);
  k_dew<<<dim3(64, B_), 256, 0, stream>>>(x1, Wxabs, stats, DEw);
  k_adj<<<dim3(8, 8, B_), 256, 0, stream>>>(DEw, x1, out);
  k_topk<<<(B_ * N_) / 4, 256, 0, stream>>>(out);
}

// Round 11
// 412.793 us; speedup vs baseline: 3.3706x; 1.0253x over previous
//
#include <hip/hip_runtime.h>
#include <hip/hip_bf16.h>

#define B_ 32
#define T_ 96
#define N_ 1024
#define ED_ 64
#define FFT_ 49
#define TOPK_ 30

// ---------------- ws layout (floats) ----------------
#define OFF_TWC   0u
#define OFF_TWS   4704u
#define OFF_XN1   9408u
#define OFF_RIN2  1615040u
#define OFF_XF    1616608u
#define OFF_X1    3713760u
#define OFF_PART  5810912u
#define OFF_STATS 5811424u
#define OFF_DEW   5811488u

// ---------------- wave helpers ----------------
__device__ __forceinline__ float wsum(float x){
  #pragma unroll
  for (int o = 32; o > 0; o >>= 1) x += __shfl_xor(x, o, 64);
  return x;
}
__device__ __forceinline__ int wsumi(int x){
  #pragma unroll
  for (int o = 32; o > 0; o >>= 1) x += __shfl_xor(x, o, 64);
  return x;
}
__device__ __forceinline__ float wmax(float x){
  #pragma unroll
  for (int o = 32; o > 0; o >>= 1) x = fmaxf(x, __shfl_xor(x, o, 64));
  return x;
}

// ---------------- K0: twiddle tables (transposed [t][f]) ----------------
__global__ void k_tw(float* __restrict__ twCt, float* __restrict__ twSt){
  int idx = blockIdx.x * 256 + threadIdx.x;
  if (idx < T_ * FFT_){
    int t = idx / FFT_, f = idx % FFT_;
    int k = (f * t) % T_;
    float ang = (float)k * 0.06544984694978736f; // 2*pi/96
    twCt[idx] = cosf(ang);
    twSt[idx] = sinf(ang);
  }
}

// ---------------- K1: DFT magnitude + axis-1 (freq) normalize ----------------
template<int F0, int NF>
__device__ __forceinline__ void dft_half(const float (*xs)[128], const float* __restrict__ twCt,
                                         const float* __restrict__ twSt, int n, float* mag, float* ssOut){
  float re[NF], im[NF];
  #pragma unroll
  for (int j = 0; j < NF; ++j){ re[j] = 0.f; im[j] = 0.f; }
  for (int t = 0; t < T_; ++t){
    float xv = xs[t][n];
    const float* c = twCt + t * FFT_ + F0;
    const float* s = twSt + t * FFT_ + F0;
    #pragma unroll
    for (int j = 0; j < NF; ++j){
      re[j] = fmaf(xv, c[j], re[j]);
      im[j] = fmaf(xv, s[j], im[j]);
    }
  }
  float ss = 0.f;
  #pragma unroll
  for (int j = 0; j < NF; ++j){
    float m = sqrtf(re[j]*re[j] + im[j]*im[j]);
    mag[j] = m; ss += m * m;
  }
  *ssOut = ss;
}

__global__ __launch_bounds__(256) void k_dft(const float* __restrict__ x, const float* __restrict__ twCt,
                                             const float* __restrict__ twSt, float* __restrict__ xn1){
  __shared__ float xs[T_][128];
  __shared__ float psum[2][128];
  int b = blockIdx.y, n0 = blockIdx.x * 128;
  int tid = threadIdx.x;
  for (int idx = tid; idx < T_ * 128; idx += 256){
    int t = idx >> 7, n = idx & 127;
    xs[t][n] = x[((size_t)b * T_ + t) * N_ + n0 + n];
  }
  __syncthreads();
  int n = tid & 127, half = tid >> 7;
  float mag[25]; float ss;
  if (half == 0) dft_half<0, 25>(xs, twCt, twSt, n, mag, &ss);
  else           dft_half<25, 24>(xs, twCt, twSt, n, mag, &ss);
  psum[half][n] = ss;
  __syncthreads();
  float rn = 1.f / fmaxf(sqrtf(psum[0][n] + psum[1][n]), 1e-12f);
  if (half == 0){
    #pragma unroll
    for (int j = 0; j < 25; ++j) xn1[((size_t)b * FFT_ + j) * N_ + n0 + n] = mag[j] * rn;
  } else {
    #pragma unroll
    for (int j = 0; j < 24; ++j) xn1[((size_t)b * FFT_ + 25 + j) * N_ + n0 + n] = mag[j] * rn;
  }
}

// ---------------- K1b: axis-2 (node) norm -> reciprocal ----------------
__global__ __launch_bounds__(256) void k_rin2(const float* __restrict__ xn1, float* __restrict__ rin2){
  int bf = blockIdx.x, tid = threadIdx.x;
  const float* p = xn1 + (size_t)bf * N_;
  float s = 0.f;
  #pragma unroll
  for (int it = 0; it < 4; ++it){ float v = p[tid + it * 256]; s += v * v; }
  s = wsum(s);
  __shared__ float sh[4];
  int lane = tid & 63, w = tid >> 6;
  if (lane == 0) sh[w] = s;
  __syncthreads();
  if (tid == 0){
    float tot = sh[0] + sh[1] + sh[2] + sh[3];
    rin2[bf] = 1.f / fmaxf(sqrtf(tot), 1e-12f);
  }
}

// ---------------- K2: xf[b,n,d] = sum_f xn2 * Wx ----------------
__global__ __launch_bounds__(256) void k_xf(const float* __restrict__ xn1, const float* __restrict__ rin2,
                                            const float* __restrict__ Wx, float* __restrict__ xf){
  __shared__ float Wp[FFT_][64];
  __shared__ float xnt[FFT_][64];
  int b = blockIdx.y, n0 = blockIdx.x * 64, tid = threadIdx.x;
  for (int idx = tid; idx < FFT_ * 64; idx += 256){
    int f = idx >> 6, d = idx & 63;
    Wp[f][d]  = Wx[idx] * rin2[b * FFT_ + f];
    xnt[f][d] = xn1[((size_t)b * FFT_ + f) * N_ + n0 + d];
  }
  __syncthreads();
  int n = tid & 63, dg = tid >> 6, d0 = dg * 16;
  float acc[16] = {};
  for (int f = 0; f < FFT_; ++f){
    float xv = xnt[f][n];
    #pragma unroll
    for (int j = 0; j < 16; ++j) acc[j] = fmaf(xv, Wp[f][d0 + j], acc[j]);
  }
  float* op = xf + ((size_t)b * N_ + n0 + n) * ED_ + d0;
  #pragma unroll
  for (int q = 0; q < 4; ++q)
    *(float4*)(op + q * 4) = make_float4(acc[q*4], acc[q*4+1], acc[q*4+2], acc[q*4+3]);
}

// ---------------- K3: x1 = relu(xedw @ Wd[n]) ----------------
__global__ __launch_bounds__(256, 4) void k_x1(const float* __restrict__ xf, const float* __restrict__ E,
                                               const float* __restrict__ T_D, const float* __restrict__ D_W,
                                               const float* __restrict__ Wd, float* __restrict__ x1){
  __shared__ float xe[B_][260];
  __shared__ float Ws[64][68];
  int nn = blockIdx.x, tid = threadIdx.x;

  // stage xedw[32][256]: separate coalesced loops, 4 batch-rows per iteration
  {
    int bb0 = tid >> 6, f = tid & 63;
    #pragma unroll 2
    for (int it = 0; it < 8; ++it){
      int b2 = bb0 + it * 4;
      size_t bn = ((size_t)b2 * N_ + nn) * ED_;
      xe[b2][f]       = xf[bn + f];
      xe[b2][128 + f] = T_D[bn + f];
      xe[b2][192 + f] = D_W[bn + f];
    }
    float ev = E[nn * ED_ + f];
    #pragma unroll
    for (int it = 0; it < 8; ++it) xe[bb0 + it * 4][64 + f] = ev;
  }

  int bb = tid >> 3, eg = tid & 7, e0 = eg * 8;
  float acc[8] = {};
  const float4* Wd4 = (const float4*)(Wd + (size_t)nn * 256 * ED_);
  for (int c = 0; c < 4; ++c){
    __syncthreads();
    #pragma unroll
    for (int it = 0; it < 4; ++it){
      int idx = tid + it * 256;
      float4 w = Wd4[c * 1024 + idx];
      int fl = idx >> 4, e = (idx & 15) * 4;
      *(float4*)(&Ws[fl][e]) = w;
    }
    __syncthreads();
    #pragma unroll 8
    for (int fl = 0; fl < 64; ++fl){
      float xv = xe[bb][c * 64 + fl];
      float4 w0 = *(const float4*)(&Ws[fl][e0]);
      float4 w1 = *(const float4*)(&Ws[fl][e0 + 4]);
      acc[0] = fmaf(xv, w0.x, acc[0]); acc[1] = fmaf(xv, w0.y, acc[1]);
      acc[2] = fmaf(xv, w0.z, acc[2]); acc[3] = fmaf(xv, w0.w, acc[3]);
      acc[4] = fmaf(xv, w1.x, acc[4]); acc[5] = fmaf(xv, w1.y, acc[5]);
      acc[6] = fmaf(xv, w1.z, acc[6]); acc[7] = fmaf(xv, w1.w, acc[7]);
    }
  }
  float* op = x1 + ((size_t)bb * N_ + nn) * ED_ + e0;
  float4 o0 = make_float4(fmaxf(acc[0],0.f), fmaxf(acc[1],0.f), fmaxf(acc[2],0.f), fmaxf(acc[3],0.f));
  float4 o1 = make_float4(fmaxf(acc[4],0.f), fmaxf(acc[5],0.f), fmaxf(acc[6],0.f), fmaxf(acc[7],0.f));
  *(float4*)(op) = o0;
  *(float4*)(op + 4) = o1;
}

// ---------------- K4a/K4b: LayerNorm stats over [N,ED] per batch ----------------
__global__ __launch_bounds__(256) void k_stats1(const float* __restrict__ x1, float2* __restrict__ part){
  int blk = blockIdx.x, b = blk >> 3, seg = blk & 7;
  const float4* p = (const float4*)(x1 + (size_t)b * 65536 + seg * 8192);
  int tid = threadIdx.x;
  float s1 = 0.f, s2 = 0.f;
  #pragma unroll
  for (int it = 0; it < 8; ++it){
    float4 v = p[tid + it * 256];
    s1 += v.x + v.y + v.z + v.w;
    s2 += v.x*v.x + v.y*v.y + v.z*v.z + v.w*v.w;
  }
  s1 = wsum(s1); s2 = wsum(s2);
  __shared__ float sh[2][4];
  int lane = tid & 63, w = tid >> 6;
  if (lane == 0){ sh[0][w] = s1; sh[1][w] = s2; }
  __syncthreads();
  if (tid == 0)
    part[blk] = make_float2(sh[0][0]+sh[0][1]+sh[0][2]+sh[0][3],
                            sh[1][0]+sh[1][1]+sh[1][2]+sh[1][3]);
}

__global__ void k_stats2(const float2* __restrict__ part, float* __restrict__ stats){
  int b = threadIdx.x;
  if (b < B_){
    float s1 = 0.f, s2 = 0.f;
    for (int j = 0; j < 8; ++j){ float2 v = part[b * 8 + j]; s1 += v.x; s2 += v.y; }
    float mu = s1 * (1.f / 65536.f);
    float var = s2 * (1.f / 65536.f) - mu * mu;
    stats[b * 2]     = mu;
    stats[b * 2 + 1] = rsqrtf(var + 1e-8f);
  }
}

// ---------------- K5: DEw = ((x1-mu)*rstd) @ Wxabs ----------------
__global__ __launch_bounds__(256) void k_dew(const float* __restrict__ x1, const float* __restrict__ Wxabs,
                                             const float* __restrict__ stats, float* __restrict__ DEw){
  __shared__ float Ws[64][68];
  __shared__ float x1s[16][68];
  __shared__ float cs[64];
  int b = blockIdx.y, n0 = blockIdx.x * 16, tid = threadIdx.x;
  for (int idx = tid; idx < 1024; idx += 256){
    float4 w = ((const float4*)Wxabs)[idx];
    int e = idx >> 4, k = (idx & 15) * 4;
    *(float4*)(&Ws[e][k]) = w;
  }
  {
    int idx = tid; // 256 float4 = whole tile
    float4 v = ((const float4*)(x1 + ((size_t)b * N_ + n0) * ED_))[idx];
    int n = idx >> 4, e = (idx & 15) * 4;
    *(float4*)(&x1s[n][e]) = v;
  }
  __syncthreads();
  if (tid < 64){
    float s = 0.f;
    for (int e = 0; e < 64; ++e) s += Ws[e][tid];
    cs[tid] = s;
  }
  __syncthreads();
  int n = tid & 15, kg = tid >> 4, k0 = kg * 4;
  float mu = stats[b * 2], rstd = stats[b * 2 + 1];
  float acc[4] = {};
  for (int e = 0; e < 64; ++e){
    float xv = x1s[n][e];
    #pragma unroll
    for (int j = 0; j < 4; ++j) acc[j] = fmaf(xv, Ws[e][k0 + j], acc[j]);
  }
  float4 o;
  o.x = rstd * (acc[0] - mu * cs[k0]);
  o.y = rstd * (acc[1] - mu * cs[k0 + 1]);
  o.z = rstd * (acc[2] - mu * cs[k0 + 2]);
  o.w = rstd * (acc[3] - mu * cs[k0 + 3]);
  *(float4*)(DEw + ((size_t)b * N_ + n0 + n) * ED_ + k0) = o;
}

// ---------------- K6: adj = relu(DEw @ x1^T) -> d_out ----------------
__global__ __launch_bounds__(256) void k_adj(const float* __restrict__ DEw, const float* __restrict__ x1,
                                             float* __restrict__ out){
  __shared__ float At[64][132];
  __shared__ float Bt[64][132];
  int b = blockIdx.z;
  int nb = blockIdx.y * 128, mb = blockIdx.x * 128;
  int tid = threadIdx.x;
  const float4* A4 = (const float4*)(DEw + ((size_t)b * N_ + nb) * ED_);
  const float4* Bq = (const float4*)(x1  + ((size_t)b * N_ + mb) * ED_);
  for (int idx = tid; idx < 2048; idx += 256){
    int r = idx >> 4, k4 = idx & 15, k0 = k4 * 4;
    float4 a = A4[r * 16 + k4];
    At[k0][r] = a.x; At[k0+1][r] = a.y; At[k0+2][r] = a.z; At[k0+3][r] = a.w;
    float4 v = Bq[r * 16 + k4];
    Bt[k0][r] = v.x; Bt[k0+1][r] = v.y; Bt[k0+2][r] = v.z; Bt[k0+3][r] = v.w;
  }
  __syncthreads();
  int tn = tid >> 4, tm = tid & 15;
  float acc[8][8] = {};
  #pragma unroll 4
  for (int k = 0; k < 64; ++k){
    const float4* Ar = (const float4*)(&At[k][0]);
    const float4* Br = (const float4*)(&Bt[k][0]);
    float4 a0 = Ar[tn * 2], a1 = Ar[tn * 2 + 1];
    float4 b0 = Br[tm * 2], b1 = Br[tm * 2 + 1];
    float av[8] = {a0.x,a0.y,a0.z,a0.w,a1.x,a1.y,a1.z,a1.w};
    float bw[8] = {b0.x,b0.y,b0.z,b0.w,b1.x,b1.y,b1.z,b1.w};
    #pragma unroll
    for (int i = 0; i < 8; ++i)
      #pragma unroll
      for (int j = 0; j < 8; ++j)
        acc[i][j] = fmaf(av[i], bw[j], acc[i][j]);
  }
  size_t obase = ((size_t)b * N_ + nb + tn * 8) * N_ + mb + tm * 8;
  #pragma unroll
  for (int i = 0; i < 8; ++i){
    float4 o0 = make_float4(fmaxf(acc[i][0],0.f), fmaxf(acc[i][1],0.f), fmaxf(acc[i][2],0.f), fmaxf(acc[i][3],0.f));
    float4 o1 = make_float4(fmaxf(acc[i][4],0.f), fmaxf(acc[i][5],0.f), fmaxf(acc[i][6],0.f), fmaxf(acc[i][7],0.f));
    *(float4*)(out + obase + (size_t)i * N_)     = o0;
    *(float4*)(out + obase + (size_t)i * N_ + 4) = o1;
  }
}

// ---------------- K7: per-row exact top-30 mask + softmax (in place) ----------------
// Count via __ballot + scalar popcount: the binary-search loop needs only
// 16 v_cmp per iteration (VALU); s_bcnt1_b64/s_add run on the scalar pipe,
// and lo/hi/count stay wave-uniform in SGPRs. Replaces 6-deep ds_swizzle
// reduction chains (was 93% VALUBusy, search-dominated).
__global__ __launch_bounds__(256) void k_topk(float* __restrict__ out){
  int row = blockIdx.x * 4 + (threadIdx.x >> 6);
  int lane = threadIdx.x & 63;
  float* rp = out + (size_t)row * N_;
  float v[16];
  #pragma unroll
  for (int q = 0; q < 4; ++q){
    float4 t = *(const float4*)(rp + lane * 16 + q * 4);
    v[q*4] = t.x; v[q*4+1] = t.y; v[q*4+2] = t.z; v[q*4+3] = t.w;
  }
  float vmax = v[0];
  #pragma unroll
  for (int j = 1; j < 16; ++j) vmax = fmaxf(vmax, v[j]);
  vmax = wmax(vmax);

  // exact 30th-largest via binary search on (non-negative) float bit patterns
  unsigned lo = 0u, hi = __float_as_uint(vmax) + 1u;
  while (hi - lo > 1u){
    unsigned mid = lo + ((hi - lo) >> 1);
    float t = __uint_as_float(mid);
    int c = 0;
    #pragma unroll
    for (int j = 0; j < 16; ++j)
      c += (int)__popcll(__ballot(v[j] >= t));
    if (c >= TOPK_) lo = mid; else hi = mid;
  }
  float thr = __uint_as_float(lo);

  int cgt = 0, eqc = 0;
  #pragma unroll
  for (int j = 0; j < 16; ++j)
    cgt += (int)__popcll(__ballot(v[j] > thr));
  #pragma unroll
  for (int j = 0; j < 16; ++j) eqc += (v[j] == thr) ? 1 : 0;
  int keq = TOPK_ - cgt;

  // exclusive scan of per-lane equal counts (index order = lane-major, j-minor)
  int sc = eqc;
  #pragma unroll
  for (int off = 1; off < 64; off <<= 1){
    int t = __shfl_up(sc, off, 64);
    if (lane >= off) sc += t;
  }
  int run = sc - eqc;

  float z = 0.f; float p[16];
  #pragma unroll
  for (int j = 0; j < 16; ++j){
    bool eq = (v[j] == thr);
    bool sel = (v[j] > thr) || (eq && (run < keq));
    run += eq ? 1 : 0;
    float e = __expf((sel ? v[j] : 0.f) - vmax);
    p[j] = e; z += e;
  }
  z = wsum(z);
  float rz = 1.f / z;
  #pragma unroll
  for (int q = 0; q < 4; ++q){
    float4 t = make_float4(p[q*4]*rz, p[q*4+1]*rz, p[q*4+2]*rz, p[q*4+3]*rz);
    *(float4*)(rp + lane * 16 + q * 4) = t;
  }
}

// ---------------- launcher ----------------
extern "C" void kernel_launch(void* const* d_in, const int* in_sizes, int n_in,
                              void* d_out, int out_size, void* d_ws, size_t ws_size,
                              hipStream_t stream){
  const float* x     = (const float*)d_in[0];
  const float* T_D   = (const float*)d_in[1];
  const float* D_W   = (const float*)d_in[2];
  const float* E     = (const float*)d_in[3];
  const float* Wx    = (const float*)d_in[4];
  const float* Wd    = (const float*)d_in[5];
  const float* Wxabs = (const float*)d_in[6];
  float* out = (float*)d_out;
  float* ws  = (float*)d_ws;

  float* twCt  = ws + OFF_TWC;
  float* twSt  = ws + OFF_TWS;
  float* xn1   = ws + OFF_XN1;
  float* rin2  = ws + OFF_RIN2;
  float* xf    = ws + OFF_XF;
  float* x1    = ws + OFF_X1;
  float2* part = (float2*)(ws + OFF_PART);
  float* stats = ws + OFF_STATS;
  float* DEw   = ws + OFF_DEW;

  k_tw<<<19, 256, 0, stream>>>(twCt, twSt);
  k_dft<<<dim3(8, B_), 256, 0, stream>>>(x, twCt, twSt, xn1);
  k_rin2<<<B_ * FFT_, 256, 0, stream>>>(xn1, rin2);
  k_xf<<<dim3(16, B_), 256, 0, stream>>>(xn1, rin2, Wx, xf);
  k_x1<<<N_, 256, 0, stream>>>(xf, E, T_D, D_W, Wd, x1);
  k_stats1<<<256, 256, 0, stream>>>(x1, part);
  k_stats2<<<1, 64, 0, stream>>>(part, stats);
  k_dew<<<dim3(64, B_), 256, 0, stream>>>(x1, Wxabs, stats, DEw);
  k_adj<<<dim3(8, 8, B_), 256, 0, stream>>>(DEw, x1, out);
  k_topk<<<(B_ * N_) / 4, 256, 0, stream>>>(out);
}

// Round 12
// 394.104 us; speedup vs baseline: 3.5304x; 1.0474x over previous
//
#include <hip/hip_runtime.h>
#include <hip/hip_bf16.h>

#define B_ 32
#define T_ 96
#define N_ 1024
#define ED_ 64
#define FFT_ 49
#define TOPK_ 30

// ---------------- ws layout (floats) ----------------
#define OFF_TWC   0u
#define OFF_TWS   4704u
#define OFF_XN1   9408u
#define OFF_RIN2  1615040u
#define OFF_XF    1616608u
#define OFF_X1    3713760u
#define OFF_PART  5810912u
#define OFF_STATS 5811424u
#define OFF_DEW   5811488u

// ---------------- wave helpers ----------------
__device__ __forceinline__ float wsum(float x){
  #pragma unroll
  for (int o = 32; o > 0; o >>= 1) x += __shfl_xor(x, o, 64);
  return x;
}
__device__ __forceinline__ int wsumi(int x){
  #pragma unroll
  for (int o = 32; o > 0; o >>= 1) x += __shfl_xor(x, o, 64);
  return x;
}
__device__ __forceinline__ float wmax(float x){
  #pragma unroll
  for (int o = 32; o > 0; o >>= 1) x = fmaxf(x, __shfl_xor(x, o, 64));
  return x;
}

// ---------------- K0: twiddle tables (transposed [t][f]) ----------------
__global__ void k_tw(float* __restrict__ twCt, float* __restrict__ twSt){
  int idx = blockIdx.x * 256 + threadIdx.x;
  if (idx < T_ * FFT_){
    int t = idx / FFT_, f = idx % FFT_;
    int k = (f * t) % T_;
    float ang = (float)k * 0.06544984694978736f; // 2*pi/96
    twCt[idx] = cosf(ang);
    twSt[idx] = sinf(ang);
  }
}

// ---------------- K1: DFT magnitude + axis-1 (freq) normalize ----------------
template<int F0, int NF>
__device__ __forceinline__ void dft_half(const float (*xs)[128], const float* __restrict__ twCt,
                                         const float* __restrict__ twSt, int n, float* mag, float* ssOut){
  float re[NF], im[NF];
  #pragma unroll
  for (int j = 0; j < NF; ++j){ re[j] = 0.f; im[j] = 0.f; }
  for (int t = 0; t < T_; ++t){
    float xv = xs[t][n];
    const float* c = twCt + t * FFT_ + F0;
    const float* s = twSt + t * FFT_ + F0;
    #pragma unroll
    for (int j = 0; j < NF; ++j){
      re[j] = fmaf(xv, c[j], re[j]);
      im[j] = fmaf(xv, s[j], im[j]);
    }
  }
  float ss = 0.f;
  #pragma unroll
  for (int j = 0; j < NF; ++j){
    float m = sqrtf(re[j]*re[j] + im[j]*im[j]);
    mag[j] = m; ss += m * m;
  }
  *ssOut = ss;
}

__global__ __launch_bounds__(256) void k_dft(const float* __restrict__ x, const float* __restrict__ twCt,
                                             const float* __restrict__ twSt, float* __restrict__ xn1){
  __shared__ float xs[T_][128];
  __shared__ float psum[2][128];
  int b = blockIdx.y, n0 = blockIdx.x * 128;
  int tid = threadIdx.x;
  for (int idx = tid; idx < T_ * 128; idx += 256){
    int t = idx >> 7, n = idx & 127;
    xs[t][n] = x[((size_t)b * T_ + t) * N_ + n0 + n];
  }
  __syncthreads();
  int n = tid & 127, half = tid >> 7;
  float mag[25]; float ss;
  if (half == 0) dft_half<0, 25>(xs, twCt, twSt, n, mag, &ss);
  else           dft_half<25, 24>(xs, twCt, twSt, n, mag, &ss);
  psum[half][n] = ss;
  __syncthreads();
  float rn = 1.f / fmaxf(sqrtf(psum[0][n] + psum[1][n]), 1e-12f);
  if (half == 0){
    #pragma unroll
    for (int j = 0; j < 25; ++j) xn1[((size_t)b * FFT_ + j) * N_ + n0 + n] = mag[j] * rn;
  } else {
    #pragma unroll
    for (int j = 0; j < 24; ++j) xn1[((size_t)b * FFT_ + 25 + j) * N_ + n0 + n] = mag[j] * rn;
  }
}

// ---------------- K1b: axis-2 (node) norm -> reciprocal ----------------
__global__ __launch_bounds__(256) void k_rin2(const float* __restrict__ xn1, float* __restrict__ rin2){
  int bf = blockIdx.x, tid = threadIdx.x;
  const float* p = xn1 + (size_t)bf * N_;
  float s = 0.f;
  #pragma unroll
  for (int it = 0; it < 4; ++it){ float v = p[tid + it * 256]; s += v * v; }
  s = wsum(s);
  __shared__ float sh[4];
  int lane = tid & 63, w = tid >> 6;
  if (lane == 0) sh[w] = s;
  __syncthreads();
  if (tid == 0){
    float tot = sh[0] + sh[1] + sh[2] + sh[3];
    rin2[bf] = 1.f / fmaxf(sqrtf(tot), 1e-12f);
  }
}

// ---------------- K2: xf[b,n,d] = sum_f xn2 * Wx ----------------
__global__ __launch_bounds__(256) void k_xf(const float* __restrict__ xn1, const float* __restrict__ rin2,
                                            const float* __restrict__ Wx, float* __restrict__ xf){
  __shared__ float Wp[FFT_][64];
  __shared__ float xnt[FFT_][64];
  int b = blockIdx.y, n0 = blockIdx.x * 64, tid = threadIdx.x;
  for (int idx = tid; idx < FFT_ * 64; idx += 256){
    int f = idx >> 6, d = idx & 63;
    Wp[f][d]  = Wx[idx] * rin2[b * FFT_ + f];
    xnt[f][d] = xn1[((size_t)b * FFT_ + f) * N_ + n0 + d];
  }
  __syncthreads();
  int n = tid & 63, dg = tid >> 6, d0 = dg * 16;
  float acc[16] = {};
  for (int f = 0; f < FFT_; ++f){
    float xv = xnt[f][n];
    #pragma unroll
    for (int j = 0; j < 16; ++j) acc[j] = fmaf(xv, Wp[f][d0 + j], acc[j]);
  }
  float* op = xf + ((size_t)b * N_ + n0 + n) * ED_ + d0;
  #pragma unroll
  for (int q = 0; q < 4; ++q)
    *(float4*)(op + q * 4) = make_float4(acc[q*4], acc[q*4+1], acc[q*4+2], acc[q*4+3]);
}

// ---------------- K3: x1 = relu(xedw @ Wd[n]) ----------------
__global__ __launch_bounds__(256, 4) void k_x1(const float* __restrict__ xf, const float* __restrict__ E,
                                               const float* __restrict__ T_D, const float* __restrict__ D_W,
                                               const float* __restrict__ Wd, float* __restrict__ x1){
  __shared__ float xe[B_][260];
  __shared__ float Ws[64][68];
  int nn = blockIdx.x, tid = threadIdx.x;

  // stage xedw[32][256]: separate coalesced loops, 4 batch-rows per iteration
  {
    int bb0 = tid >> 6, f = tid & 63;
    #pragma unroll 2
    for (int it = 0; it < 8; ++it){
      int b2 = bb0 + it * 4;
      size_t bn = ((size_t)b2 * N_ + nn) * ED_;
      xe[b2][f]       = xf[bn + f];
      xe[b2][128 + f] = T_D[bn + f];
      xe[b2][192 + f] = D_W[bn + f];
    }
    float ev = E[nn * ED_ + f];
    #pragma unroll
    for (int it = 0; it < 8; ++it) xe[bb0 + it * 4][64 + f] = ev;
  }

  int bb = tid >> 3, eg = tid & 7, e0 = eg * 8;
  float acc[8] = {};
  const float4* Wd4 = (const float4*)(Wd + (size_t)nn * 256 * ED_);
  for (int c = 0; c < 4; ++c){
    __syncthreads();
    #pragma unroll
    for (int it = 0; it < 4; ++it){
      int idx = tid + it * 256;
      float4 w = Wd4[c * 1024 + idx];
      int fl = idx >> 4, e = (idx & 15) * 4;
      *(float4*)(&Ws[fl][e]) = w;
    }
    __syncthreads();
    #pragma unroll 8
    for (int fl = 0; fl < 64; ++fl){
      float xv = xe[bb][c * 64 + fl];
      float4 w0 = *(const float4*)(&Ws[fl][e0]);
      float4 w1 = *(const float4*)(&Ws[fl][e0 + 4]);
      acc[0] = fmaf(xv, w0.x, acc[0]); acc[1] = fmaf(xv, w0.y, acc[1]);
      acc[2] = fmaf(xv, w0.z, acc[2]); acc[3] = fmaf(xv, w0.w, acc[3]);
      acc[4] = fmaf(xv, w1.x, acc[4]); acc[5] = fmaf(xv, w1.y, acc[5]);
      acc[6] = fmaf(xv, w1.z, acc[6]); acc[7] = fmaf(xv, w1.w, acc[7]);
    }
  }
  float* op = x1 + ((size_t)bb * N_ + nn) * ED_ + e0;
  float4 o0 = make_float4(fmaxf(acc[0],0.f), fmaxf(acc[1],0.f), fmaxf(acc[2],0.f), fmaxf(acc[3],0.f));
  float4 o1 = make_float4(fmaxf(acc[4],0.f), fmaxf(acc[5],0.f), fmaxf(acc[6],0.f), fmaxf(acc[7],0.f));
  *(float4*)(op) = o0;
  *(float4*)(op + 4) = o1;
}

// ---------------- K4a/K4b: LayerNorm stats over [N,ED] per batch ----------------
__global__ __launch_bounds__(256) void k_stats1(const float* __restrict__ x1, float2* __restrict__ part){
  int blk = blockIdx.x, b = blk >> 3, seg = blk & 7;
  const float4* p = (const float4*)(x1 + (size_t)b * 65536 + seg * 8192);
  int tid = threadIdx.x;
  float s1 = 0.f, s2 = 0.f;
  #pragma unroll
  for (int it = 0; it < 8; ++it){
    float4 v = p[tid + it * 256];
    s1 += v.x + v.y + v.z + v.w;
    s2 += v.x*v.x + v.y*v.y + v.z*v.z + v.w*v.w;
  }
  s1 = wsum(s1); s2 = wsum(s2);
  __shared__ float sh[2][4];
  int lane = tid & 63, w = tid >> 6;
  if (lane == 0){ sh[0][w] = s1; sh[1][w] = s2; }
  __syncthreads();
  if (tid == 0)
    part[blk] = make_float2(sh[0][0]+sh[0][1]+sh[0][2]+sh[0][3],
                            sh[1][0]+sh[1][1]+sh[1][2]+sh[1][3]);
}

__global__ void k_stats2(const float2* __restrict__ part, float* __restrict__ stats){
  int b = threadIdx.x;
  if (b < B_){
    float s1 = 0.f, s2 = 0.f;
    for (int j = 0; j < 8; ++j){ float2 v = part[b * 8 + j]; s1 += v.x; s2 += v.y; }
    float mu = s1 * (1.f / 65536.f);
    float var = s2 * (1.f / 65536.f) - mu * mu;
    stats[b * 2]     = mu;
    stats[b * 2 + 1] = rsqrtf(var + 1e-8f);
  }
}

// ---------------- K5: DEw = ((x1-mu)*rstd) @ Wxabs ----------------
__global__ __launch_bounds__(256) void k_dew(const float* __restrict__ x1, const float* __restrict__ Wxabs,
                                             const float* __restrict__ stats, float* __restrict__ DEw){
  __shared__ float Ws[64][68];
  __shared__ float x1s[16][68];
  __shared__ float cs[64];
  int b = blockIdx.y, n0 = blockIdx.x * 16, tid = threadIdx.x;
  for (int idx = tid; idx < 1024; idx += 256){
    float4 w = ((const float4*)Wxabs)[idx];
    int e = idx >> 4, k = (idx & 15) * 4;
    *(float4*)(&Ws[e][k]) = w;
  }
  {
    int idx = tid; // 256 float4 = whole tile
    float4 v = ((const float4*)(x1 + ((size_t)b * N_ + n0) * ED_))[idx];
    int n = idx >> 4, e = (idx & 15) * 4;
    *(float4*)(&x1s[n][e]) = v;
  }
  __syncthreads();
  if (tid < 64){
    float s = 0.f;
    for (int e = 0; e < 64; ++e) s += Ws[e][tid];
    cs[tid] = s;
  }
  __syncthreads();
  int n = tid & 15, kg = tid >> 4, k0 = kg * 4;
  float mu = stats[b * 2], rstd = stats[b * 2 + 1];
  float acc[4] = {};
  for (int e = 0; e < 64; ++e){
    float xv = x1s[n][e];
    #pragma unroll
    for (int j = 0; j < 4; ++j) acc[j] = fmaf(xv, Ws[e][k0 + j], acc[j]);
  }
  float4 o;
  o.x = rstd * (acc[0] - mu * cs[k0]);
  o.y = rstd * (acc[1] - mu * cs[k0 + 1]);
  o.z = rstd * (acc[2] - mu * cs[k0 + 2]);
  o.w = rstd * (acc[3] - mu * cs[k0 + 3]);
  *(float4*)(DEw + ((size_t)b * N_ + n0 + n) * ED_ + k0) = o;
}

// ---------------- K6: adj = relu(DEw @ x1^T) -> d_out ----------------
__global__ __launch_bounds__(256) void k_adj(const float* __restrict__ DEw, const float* __restrict__ x1,
                                             float* __restrict__ out){
  __shared__ float At[64][132];
  __shared__ float Bt[64][132];
  int b = blockIdx.z;
  int nb = blockIdx.y * 128, mb = blockIdx.x * 128;
  int tid = threadIdx.x;
  const float4* A4 = (const float4*)(DEw + ((size_t)b * N_ + nb) * ED_);
  const float4* Bq = (const float4*)(x1  + ((size_t)b * N_ + mb) * ED_);
  for (int idx = tid; idx < 2048; idx += 256){
    int r = idx >> 4, k4 = idx & 15, k0 = k4 * 4;
    float4 a = A4[r * 16 + k4];
    At[k0][r] = a.x; At[k0+1][r] = a.y; At[k0+2][r] = a.z; At[k0+3][r] = a.w;
    float4 v = Bq[r * 16 + k4];
    Bt[k0][r] = v.x; Bt[k0+1][r] = v.y; Bt[k0+2][r] = v.z; Bt[k0+3][r] = v.w;
  }
  __syncthreads();
  int tn = tid >> 4, tm = tid & 15;
  float acc[8][8] = {};
  #pragma unroll 4
  for (int k = 0; k < 64; ++k){
    const float4* Ar = (const float4*)(&At[k][0]);
    const float4* Br = (const float4*)(&Bt[k][0]);
    float4 a0 = Ar[tn * 2], a1 = Ar[tn * 2 + 1];
    float4 b0 = Br[tm * 2], b1 = Br[tm * 2 + 1];
    float av[8] = {a0.x,a0.y,a0.z,a0.w,a1.x,a1.y,a1.z,a1.w};
    float bw[8] = {b0.x,b0.y,b0.z,b0.w,b1.x,b1.y,b1.z,b1.w};
    #pragma unroll
    for (int i = 0; i < 8; ++i)
      #pragma unroll
      for (int j = 0; j < 8; ++j)
        acc[i][j] = fmaf(av[i], bw[j], acc[i][j]);
  }
  size_t obase = ((size_t)b * N_ + nb + tn * 8) * N_ + mb + tm * 8;
  #pragma unroll
  for (int i = 0; i < 8; ++i){
    float4 o0 = make_float4(fmaxf(acc[i][0],0.f), fmaxf(acc[i][1],0.f), fmaxf(acc[i][2],0.f), fmaxf(acc[i][3],0.f));
    float4 o1 = make_float4(fmaxf(acc[i][4],0.f), fmaxf(acc[i][5],0.f), fmaxf(acc[i][6],0.f), fmaxf(acc[i][7],0.f));
    *(float4*)(out + obase + (size_t)i * N_)     = o0;
    *(float4*)(out + obase + (size_t)i * N_ + 4) = o1;
  }
}

// ---------------- K7: per-row exact top-30 mask + softmax (in place) ----------------
// Bisection with EARLY EXIT: if count(v >= t) == 30 for any probe t, then
// {v >= t} IS the exact top-30 set (a separator excludes ties by construction)
// -> select directly, skip tie-breaking scan. Random continuous data finds a
// separator in ~12-18 iters instead of always 30 (the serial chain was the
// residual cost: 61% VALUBusy at 30% HBM). True-tie rows fall through to the
// exact lowest-index-first path (unchanged semantics).
__global__ __launch_bounds__(256) void k_topk(float* __restrict__ out){
  int row = blockIdx.x * 4 + (threadIdx.x >> 6);
  int lane = threadIdx.x & 63;
  float* rp = out + (size_t)row * N_;
  float v[16];
  #pragma unroll
  for (int q = 0; q < 4; ++q){
    float4 t = *(const float4*)(rp + lane * 16 + q * 4);
    v[q*4] = t.x; v[q*4+1] = t.y; v[q*4+2] = t.z; v[q*4+3] = t.w;
  }
  float vmax = v[0];
  #pragma unroll
  for (int j = 1; j < 16; ++j) vmax = fmaxf(vmax, v[j]);
  vmax = wmax(vmax);

  // binary search on (non-negative) float bit patterns, early exit on separator
  unsigned lo = 0u, hi = __float_as_uint(vmax) + 1u;
  bool sep = false;
  float thr = 0.f;
  while (hi - lo > 1u){
    unsigned mid = lo + ((hi - lo) >> 1);
    float t = __uint_as_float(mid);
    int c = 0;
    #pragma unroll
    for (int j = 0; j < 16; ++j)
      c += (int)__popcll(__ballot(v[j] >= t));
    if (c == TOPK_){ thr = t; sep = true; break; }
    if (c > TOPK_) lo = mid; else hi = mid;
  }

  float z = 0.f; float p[16];
  if (sep){
    // exact top-30 = {v >= thr}; no ties possible at a separator
    #pragma unroll
    for (int j = 0; j < 16; ++j){
      float e = __expf(((v[j] >= thr) ? v[j] : 0.f) - vmax);
      p[j] = e; z += e;
    }
  } else {
    thr = __uint_as_float(lo);
    int cgt = 0, eqc = 0;
    #pragma unroll
    for (int j = 0; j < 16; ++j)
      cgt += (int)__popcll(__ballot(v[j] > thr));
    #pragma unroll
    for (int j = 0; j < 16; ++j) eqc += (v[j] == thr) ? 1 : 0;
    int keq = TOPK_ - cgt;

    // exclusive scan of per-lane equal counts (index order = lane-major, j-minor)
    int sc = eqc;
    #pragma unroll
    for (int off = 1; off < 64; off <<= 1){
      int t = __shfl_up(sc, off, 64);
      if (lane >= off) sc += t;
    }
    int run = sc - eqc;

    #pragma unroll
    for (int j = 0; j < 16; ++j){
      bool eq = (v[j] == thr);
      bool sel = (v[j] > thr) || (eq && (run < keq));
      run += eq ? 1 : 0;
      float e = __expf((sel ? v[j] : 0.f) - vmax);
      p[j] = e; z += e;
    }
  }
  z = wsum(z);
  float rz = 1.f / z;
  #pragma unroll
  for (int q = 0; q < 4; ++q){
    float4 t = make_float4(p[q*4]*rz, p[q*4+1]*rz, p[q*4+2]*rz, p[q*4+3]*rz);
    *(float4*)(rp + lane * 16 + q * 4) = t;
  }
}

// ---------------- launcher ----------------
extern "C" void kernel_launch(void* const* d_in, const int* in_sizes, int n_in,
                              void* d_out, int out_size, void* d_ws, size_t ws_size,
                              hipStream_t stream){
  const float* x     = (const float*)d_in[0];
  const float* T_D   = (const float*)d_in[1];
  const float* D_W   = (const float*)d_in[2];
  const float* E     = (const float*)d_in[3];
  const float* Wx    = (const float*)d_in[4];
  const float* Wd    = (const float*)d_in[5];
  const float* Wxabs = (const float*)d_in[6];
  float* out = (float*)d_out;
  float* ws  = (float*)d_ws;

  float* twCt  = ws + OFF_TWC;
  float* twSt  = ws + OFF_TWS;
  float* xn1   = ws + OFF_XN1;
  float* rin2  = ws + OFF_RIN2;
  float* xf    = ws + OFF_XF;
  float* x1    = ws + OFF_X1;
  float2* part = (float2*)(ws + OFF_PART);
  float* stats = ws + OFF_STATS;
  float* DEw   = ws + OFF_DEW;

  k_tw<<<19, 256, 0, stream>>>(twCt, twSt);
  k_dft<<<dim3(8, B_), 256, 0, stream>>>(x, twCt, twSt, xn1);
  k_rin2<<<B_ * FFT_, 256, 0, stream>>>(xn1, rin2);
  k_xf<<<dim3(16, B_), 256, 0, stream>>>(xn1, rin2, Wx, xf);
  k_x1<<<N_, 256, 0, stream>>>(xf, E, T_D, D_W, Wd, x1);
  k_stats1<<<256, 256, 0, stream>>>(x1, part);
  k_stats2<<<1, 64, 0, stream>>>(part, stats);
  k_dew<<<dim3(64, B_), 256, 0, stream>>>(x1, Wxabs, stats, DEw);
  k_adj<<<dim3(8, 8, B_), 256, 0, stream>>>(DEw, x1, out);
  k_topk<<<(B_ * N_) / 4, 256, 0, stream>>>(out);
}